// Round 1
// baseline (500.322 us; speedup 1.0000x reference)
//
#include <hip/hip_runtime.h>
#include <math.h>

#define BB 2
#define CC 192
#define NN 16384
#define KK 16
#define COUT 192
#define MM (BB * NN)          // 32768 points
#define EPSF 1e-5f

// ---------------------------------------------------------------------------
// Kernel 0: zero the BN accumulator (sum, sumsq) -- 2*COUT floats
// ---------------------------------------------------------------------------
__global__ void k_zero(float* __restrict__ p, int n) {
    int i = blockIdx.x * blockDim.x + threadIdx.x;
    if (i < n) p[i] = 0.0f;
}

// ---------------------------------------------------------------------------
// Kernel 1: transpose x [B,C,N] -> xt [B,N,C]   (point-major for gathers)
// ---------------------------------------------------------------------------
__global__ __launch_bounds__(256) void k_transpose_x(const float* __restrict__ x,
                                                     float* __restrict__ xt) {
    __shared__ float tile[32][33];
    int b = blockIdx.z;
    int n0 = blockIdx.x * 32;
    int c0 = blockIdx.y * 32;
    int tx = threadIdx.x, ty = threadIdx.y;  // (32,8)
    #pragma unroll
    for (int j = 0; j < 32; j += 8) {
        tile[ty + j][tx] = x[((size_t)b * CC + (c0 + ty + j)) * NN + n0 + tx];
    }
    __syncthreads();
    #pragma unroll
    for (int j = 0; j < 32; j += 8) {
        xt[((size_t)b * NN + (n0 + ty + j)) * CC + c0 + tx] = tile[tx][ty + j];
    }
}

// ---------------------------------------------------------------------------
// Kernel 2: max-relative gather. mr[b,n,c] = max_k( xt[b,j_k,c] - xt[b,i_k,c] )
// One block (192 threads = 3 waves) per point.
// ---------------------------------------------------------------------------
__global__ __launch_bounds__(192) void k_gather_mr(const float* __restrict__ xt,
                                                   const int* __restrict__ edge,
                                                   float* __restrict__ mr) {
    int n = blockIdx.x;
    int b = blockIdx.y;
    int t = threadIdx.x;  // channel
    __shared__ int sj[KK], si[KK];
    if (t < KK) {
        sj[t] = edge[(size_t)b * NN * KK + (size_t)n * KK + t];                      // edge_index[0]
        si[t] = edge[(size_t)BB * NN * KK + (size_t)b * NN * KK + (size_t)n * KK + t]; // edge_index[1]
    }
    __syncthreads();
    const float* base = xt + (size_t)b * NN * CC;
    float m = -INFINITY;
    #pragma unroll
    for (int k = 0; k < KK; ++k) {
        float vj = base[(size_t)sj[k] * CC + t];
        float vi = base[(size_t)si[k] * CC + t];
        m = fmaxf(m, vj - vi);
    }
    mr[((size_t)b * NN + n) * CC + t] = m;
}

// ---------------------------------------------------------------------------
// Kernel 3: GEMM  h[m,o] = sum_c We[o,c]*xt[m,c] + Wo[o,c]*mr[m,c]
//   We[o,c] = W[o, 2c], Wo[o,c] = W[o, 2c+1]  (interleaved-channel cat)
//   b_conv is dropped: a per-channel constant cancels in training-mode BN.
//   Also accumulates per-channel sum / sumsq for BN via atomics.
// Tile: 64 m x 64 o per block (256 threads, 4x4 micro-tile), BK=32.
// ---------------------------------------------------------------------------
__global__ __launch_bounds__(256) void k_gemm(const float* __restrict__ xt,
                                              const float* __restrict__ mr,
                                              const float* __restrict__ W,
                                              float* __restrict__ h,
                                              float* __restrict__ sums) {
    __shared__ float ax[32][65];
    __shared__ float am[32][65];
    __shared__ float we[32][64];
    __shared__ float wo[32][64];
    int m0 = blockIdx.x * 64;
    int o0 = blockIdx.y * 64;
    int t = threadIdx.x;
    int tx = t & 15, ty = t >> 4;
    float acc[4][4] = {};
    for (int cc = 0; cc < CC; cc += 32) {
        #pragma unroll
        for (int r = 0; r < 8; ++r) {
            int idx = t + r * 256;  // 0..2047
            int mm_ = idx >> 5;
            int c2 = idx & 31;
            ax[c2][mm_] = xt[(size_t)(m0 + mm_) * CC + cc + c2];
            am[c2][mm_] = mr[(size_t)(m0 + mm_) * CC + cc + c2];
        }
        #pragma unroll
        for (int r = 0; r < 8; ++r) {
            int idx = t + r * 256;
            int oo = idx & 63;
            int c2 = idx >> 6;
            we[c2][oo] = W[(size_t)(o0 + oo) * (2 * CC) + 2 * (cc + c2)];
            wo[c2][oo] = W[(size_t)(o0 + oo) * (2 * CC) + 2 * (cc + c2) + 1];
        }
        __syncthreads();
        #pragma unroll
        for (int c = 0; c < 32; ++c) {
            float axv[4], amv[4], wev[4], wov[4];
            #pragma unroll
            for (int q = 0; q < 4; ++q) {
                axv[q] = ax[c][tx * 4 + q];
                amv[q] = am[c][tx * 4 + q];
                wev[q] = we[c][ty * 4 + q];
                wov[q] = wo[c][ty * 4 + q];
            }
            #pragma unroll
            for (int i = 0; i < 4; ++i)
                #pragma unroll
                for (int j = 0; j < 4; ++j)
                    acc[i][j] += axv[i] * wev[j] + amv[i] * wov[j];
        }
        __syncthreads();
    }
    // write h (point-major: h[m][o])
    #pragma unroll
    for (int i = 0; i < 4; ++i) {
        int m = m0 + tx * 4 + i;
        #pragma unroll
        for (int j = 0; j < 4; ++j) {
            h[(size_t)m * COUT + o0 + ty * 4 + j] = acc[i][j];
        }
    }
    // BN partial sums: reduce over the 64 m's of this block, per o
    #pragma unroll
    for (int j = 0; j < 4; ++j) {
        float s = 0.0f, s2 = 0.0f;
        #pragma unroll
        for (int i = 0; i < 4; ++i) {
            float v = acc[i][j];
            s += v;
            s2 += v * v;
        }
        #pragma unroll
        for (int off = 1; off < 16; off <<= 1) {
            s += __shfl_xor(s, off);
            s2 += __shfl_xor(s2, off);
        }
        if (tx == 0) {
            int o = o0 + ty * 4 + j;
            atomicAdd(&sums[o], s);
            atomicAdd(&sums[COUT + o], s2);
        }
    }
}

// ---------------------------------------------------------------------------
// Kernel 4: finalize BN -> per-channel scale/shift
// ---------------------------------------------------------------------------
__global__ void k_bn_finalize(const float* __restrict__ sums,
                              const float* __restrict__ gamma,
                              const float* __restrict__ beta,
                              float* __restrict__ sc_sh) {
    int o = threadIdx.x;  // 192
    float inv_m = 1.0f / (float)MM;
    float mean = sums[o] * inv_m;
    float var = sums[COUT + o] * inv_m - mean * mean;
    float scale = gamma[o] * rsqrtf(var + EPSF);
    sc_sh[o] = scale;
    sc_sh[COUT + o] = beta[o] - mean * scale;
}

// ---------------------------------------------------------------------------
// Kernel 5: BN + exact GELU + transpose h [B,N,O] -> out [B,O,N]
// ---------------------------------------------------------------------------
__global__ __launch_bounds__(256) void k_bn_gelu_out(const float* __restrict__ h,
                                                     const float* __restrict__ sc_sh,
                                                     float* __restrict__ out) {
    __shared__ float tile[32][33];
    int b = blockIdx.z;
    int n0 = blockIdx.x * 32;
    int o0 = blockIdx.y * 32;
    int tx = threadIdx.x, ty = threadIdx.y;  // (32,8)
    #pragma unroll
    for (int j = 0; j < 32; j += 8) {
        int o = o0 + tx;
        float v = h[((size_t)b * NN + n0 + ty + j) * COUT + o];
        v = v * sc_sh[o] + sc_sh[COUT + o];
        float g = 0.5f * v * (1.0f + erff(v * 0.70710678118654752440f));
        tile[ty + j][tx] = g;
    }
    __syncthreads();
    #pragma unroll
    for (int j = 0; j < 32; j += 8) {
        out[((size_t)b * COUT + (o0 + ty + j)) * NN + n0 + tx] = tile[tx][ty + j];
    }
}

// ---------------------------------------------------------------------------
extern "C" void kernel_launch(void* const* d_in, const int* in_sizes, int n_in,
                              void* d_out, int out_size, void* d_ws, size_t ws_size,
                              hipStream_t stream) {
    const float* x = (const float*)d_in[0];
    const float* W = (const float*)d_in[1];
    // d_in[2] = b_conv: unused (cancels in BN)
    const float* gamma = (const float*)d_in[3];
    const float* beta = (const float*)d_in[4];
    const int* edge = (const int*)d_in[5];
    float* out = (float*)d_out;

    float* xt = (float*)d_ws;                     // [M, C]
    float* mr = xt + (size_t)MM * CC;             // [M, C]
    float* h = mr + (size_t)MM * CC;              // [M, COUT]
    float* sums = h + (size_t)MM * COUT;          // [2*COUT]
    float* sc_sh = sums + 2 * COUT;               // [2*COUT]

    k_zero<<<1, 2 * COUT, 0, stream>>>(sums, 2 * COUT);

    dim3 tgrid(NN / 32, CC / 32, BB);
    k_transpose_x<<<tgrid, dim3(32, 8), 0, stream>>>(x, xt);

    k_gather_mr<<<dim3(NN, BB), 192, 0, stream>>>(xt, edge, mr);

    k_gemm<<<dim3(MM / 64, COUT / 64), 256, 0, stream>>>(xt, mr, W, h, sums);

    k_bn_finalize<<<1, COUT, 0, stream>>>(sums, gamma, beta, sc_sh);

    dim3 ogrid(NN / 32, COUT / 32, BB);
    k_bn_gelu_out<<<ogrid, dim3(32, 8), 0, stream>>>(h, sc_sh, out);
}

// Round 2
// 94.205 us; speedup vs baseline: 5.3110x; 5.3110x over previous
//
#include <hip/hip_runtime.h>
#include <math.h>

#define BB 2
#define CC 192
#define NN 16384
#define KK 16
#define COUT 192
#define MM (BB * NN)          // 32768 points
#define KDIM (2 * CC)         // 384 = GEMM K
#define EPSF 1e-5f

typedef __attribute__((ext_vector_type(8))) short short8;
typedef __attribute__((ext_vector_type(4))) float f32x4;

static __device__ __forceinline__ float bf16_to_f32(unsigned int u16) {
    return __uint_as_float(u16 << 16);
}
static __device__ __forceinline__ unsigned short f32_to_bf16(float f) {
    unsigned int u = __float_as_uint(f);
    unsigned int r = (u + 0x7fffu + ((u >> 16) & 1u)) >> 16;  // RNE
    return (unsigned short)r;
}

// ---------------------------------------------------------------------------
// Kernel 0: zero BN accumulators
// ---------------------------------------------------------------------------
__global__ void k_zero(float* __restrict__ p, int n) {
    int i = blockIdx.x * blockDim.x + threadIdx.x;
    if (i < n) p[i] = 0.0f;
}

// ---------------------------------------------------------------------------
// Kernel 1: transpose+cast x [B,C,N] f32 -> xt [B,N,C] bf16
// ---------------------------------------------------------------------------
__global__ __launch_bounds__(256) void k_transpose_x(const float* __restrict__ x,
                                                     unsigned short* __restrict__ xt) {
    __shared__ float tile[32][33];
    int b = blockIdx.z;
    int n0 = blockIdx.x * 32;
    int c0 = blockIdx.y * 32;
    int tx = threadIdx.x, ty = threadIdx.y;  // (32,8)
    #pragma unroll
    for (int j = 0; j < 32; j += 8)
        tile[ty + j][tx] = x[((size_t)b * CC + (c0 + ty + j)) * NN + n0 + tx];
    __syncthreads();
    #pragma unroll
    for (int j = 0; j < 32; j += 8)
        xt[((size_t)b * NN + (n0 + ty + j)) * CC + c0 + tx] = f32_to_bf16(tile[tx][ty + j]);
}

// ---------------------------------------------------------------------------
// Kernel 2: gather + max-relative + interleave.
// xcat[m][2c] = xs_c (bf16), xcat[m][2c+1] = mr_c (bf16).
// Block = 192 threads handling 2 points; thread = one dword (2 channels).
// ---------------------------------------------------------------------------
__global__ __launch_bounds__(192) void k_gather(const unsigned int* __restrict__ xt32,
                                                const int* __restrict__ edge,
                                                uint2* __restrict__ xcat2) {
    __shared__ int sidx[2][2][KK];  // [point][j/i][k]
    int m0 = blockIdx.x * 2;
    int t = threadIdx.x;
    if (t < 64) {
        int p = t >> 5, s = (t >> 4) & 1, k = t & 15;
        int m = m0 + p, b = m >> 14, n = m & (NN - 1);
        sidx[p][s][k] = edge[(((size_t)s * BB + b) * NN + n) * KK + k];
    }
    __syncthreads();
    int p = t / 96, c2 = t % 96;  // c2: dword index (channels 2c2, 2c2+1)
    int m = m0 + p, b = m >> 14, n = m & (NN - 1);
    const unsigned int* base = xt32 + (size_t)b * NN * 96;
    float mx0 = -INFINITY, mx1 = -INFINITY;
    #pragma unroll
    for (int k = 0; k < KK; ++k) {
        unsigned int vj = base[(size_t)sidx[p][0][k] * 96 + c2];
        unsigned int vi = base[(size_t)sidx[p][1][k] * 96 + c2];
        mx0 = fmaxf(mx0, bf16_to_f32(vj & 0xffffu) - bf16_to_f32(vi & 0xffffu));
        mx1 = fmaxf(mx1, bf16_to_f32(vj >> 16) - bf16_to_f32(vi >> 16));
    }
    unsigned int xv = base[(size_t)n * 96 + c2];
    uint2 o;
    o.x = (xv & 0xffffu) | ((unsigned int)f32_to_bf16(mx0) << 16);
    o.y = (xv >> 16) | ((unsigned int)f32_to_bf16(mx1) << 16);
    xcat2[(size_t)m * 96 + c2] = o;
}

// ---------------------------------------------------------------------------
// Kernel 3: cast W f32 [COUT][2C] -> bf16 (layout already matches xcat's k)
// ---------------------------------------------------------------------------
__global__ void k_wcast(const float* __restrict__ W, unsigned short* __restrict__ Wb) {
    int i = blockIdx.x * 256 + threadIdx.x;
    if (i < COUT * KDIM) Wb[i] = f32_to_bf16(W[i]);
}

// ---------------------------------------------------------------------------
// Kernel 4: MFMA GEMM  h[m][o] = sum_k xcat[m][k] * Wb[o][k]  (bf16 -> f32 -> bf16)
// Block: 512 thr (8 waves), tile BM=128 x O=192, BK=64. Grid = 256 (1/CU).
// Wave w owns m-rows [w*16, w*16+16) x all 192 o (12 o-tiles).
// LDS rows are 128 B; XOR-swizzle byte ^= (row&7)<<4 on write AND read.
// ---------------------------------------------------------------------------
#define BMT 128
#define BKT 64
__global__ __launch_bounds__(512) void k_gemm(const unsigned short* __restrict__ xcat,
                                              const unsigned short* __restrict__ Wb,
                                              unsigned short* __restrict__ h) {
    __shared__ __align__(16) char ldsA[BMT * 128];    // 16 KB
    __shared__ __align__(16) char ldsB[COUT * 128];   // 24 KB
    int t = threadIdx.x;
    int m0 = blockIdx.x * BMT;
    int w = t >> 6, l = t & 63, lo = l & 15, q4 = l >> 4;
    f32x4 acc[12];
    #pragma unroll
    for (int i = 0; i < 12; ++i) acc[i] = (f32x4){0.f, 0.f, 0.f, 0.f};

    for (int ks = 0; ks < KDIM / BKT; ++ks) {
        int k0 = ks * BKT;
        if (ks) __syncthreads();
        // stage A: 128 rows x 128 B
        #pragma unroll
        for (int it = 0; it < 2; ++it) {
            int r = (t >> 3) + it * 64, c = t & 7;
            uint4 v = *(const uint4*)(xcat + (size_t)(m0 + r) * KDIM + k0 + c * 8);
            *(uint4*)(ldsA + r * 128 + ((c * 16) ^ ((r & 7) << 4))) = v;
        }
        // stage B: 192 rows x 128 B
        #pragma unroll
        for (int it = 0; it < 3; ++it) {
            int r = (t >> 3) + it * 64, c = t & 7;
            uint4 v = *(const uint4*)(Wb + (size_t)r * KDIM + k0 + c * 8);
            *(uint4*)(ldsB + r * 128 + ((c * 16) ^ ((r & 7) << 4))) = v;
        }
        __syncthreads();
        #pragma unroll
        for (int kh = 0; kh < 2; ++kh) {
            int cb = kh * 64 + q4 * 16;  // byte offset of this lane's 8 bf16 along k
            int rA = w * 16 + lo;
            short8 a = *(const short8*)(ldsA + rA * 128 + (cb ^ ((rA & 7) << 4)));
            #pragma unroll
            for (int ot = 0; ot < 12; ++ot) {
                int rB = ot * 16 + lo;
                short8 bf = *(const short8*)(ldsB + rB * 128 + (cb ^ ((rB & 7) << 4)));
                acc[ot] = __builtin_amdgcn_mfma_f32_16x16x32_bf16(a, bf, acc[ot], 0, 0, 0);
            }
        }
    }
    // epilogue: C/D layout col=lane&15 (=o), row=(lane>>4)*4+reg (=m)
    int mrow = m0 + w * 16 + q4 * 4;
    #pragma unroll
    for (int ot = 0; ot < 12; ++ot) {
        int o = ot * 16 + lo;
        #pragma unroll
        for (int r = 0; r < 4; ++r)
            h[(size_t)(mrow + r) * COUT + o] = f32_to_bf16(acc[ot][r]);
    }
}

// ---------------------------------------------------------------------------
// Kernel 5: BN statistics over h (coalesced row reads, per-block column sums)
// ---------------------------------------------------------------------------
__global__ __launch_bounds__(192) void k_stats(const unsigned short* __restrict__ h,
                                               float* __restrict__ sums) {
    int o = threadIdx.x;
    int m0 = blockIdx.x * (MM / 128);
    float s = 0.f, s2 = 0.f;
    for (int r = 0; r < MM / 128; ++r) {
        float v = bf16_to_f32(h[(size_t)(m0 + r) * COUT + o]);
        s += v;
        s2 += v * v;
    }
    atomicAdd(&sums[o], s);
    atomicAdd(&sums[COUT + o], s2);
}

// ---------------------------------------------------------------------------
// Kernel 6: finalize BN -> per-channel scale/shift
// ---------------------------------------------------------------------------
__global__ void k_bn_finalize(const float* __restrict__ sums,
                              const float* __restrict__ gamma,
                              const float* __restrict__ beta,
                              float* __restrict__ sc_sh) {
    int o = threadIdx.x;
    float inv_m = 1.0f / (float)MM;
    float mean = sums[o] * inv_m;
    float var = sums[COUT + o] * inv_m - mean * mean;
    float scale = gamma[o] * rsqrtf(var + EPSF);
    sc_sh[o] = scale;
    sc_sh[COUT + o] = beta[o] - mean * scale;
}

// ---------------------------------------------------------------------------
// Kernel 7: BN + exact GELU + transpose h [m][o] -> out [B,O,N] f32
// ---------------------------------------------------------------------------
__global__ __launch_bounds__(256) void k_out(const unsigned short* __restrict__ h,
                                             const float* __restrict__ sc_sh,
                                             float* __restrict__ out) {
    __shared__ float tile[32][33];
    int b = blockIdx.z;
    int n0 = blockIdx.x * 32;
    int o0 = blockIdx.y * 32;
    int tx = threadIdx.x, ty = threadIdx.y;  // (32,8)
    #pragma unroll
    for (int j = 0; j < 32; j += 8) {
        int o = o0 + tx;
        float v = bf16_to_f32(h[((size_t)b * NN + n0 + ty + j) * COUT + o]);
        v = v * sc_sh[o] + sc_sh[COUT + o];
        tile[ty + j][tx] = 0.5f * v * (1.0f + erff(v * 0.70710678118654752440f));
    }
    __syncthreads();
    #pragma unroll
    for (int j = 0; j < 32; j += 8)
        out[((size_t)b * COUT + (o0 + ty + j)) * NN + n0 + tx] = tile[tx][ty + j];
}

// ---------------------------------------------------------------------------
extern "C" void kernel_launch(void* const* d_in, const int* in_sizes, int n_in,
                              void* d_out, int out_size, void* d_ws, size_t ws_size,
                              hipStream_t stream) {
    const float* x = (const float*)d_in[0];
    const float* W = (const float*)d_in[1];
    // d_in[2] = b_conv: cancels in training-mode BN
    const float* gamma = (const float*)d_in[3];
    const float* beta = (const float*)d_in[4];
    const int* edge = (const int*)d_in[5];
    float* out = (float*)d_out;

    char* ws = (char*)d_ws;
    unsigned short* xt = (unsigned short*)ws;                 // [M][C] bf16
    ws += (size_t)MM * CC * 2;
    unsigned short* xcat = (unsigned short*)ws;               // [M][2C] bf16
    ws += (size_t)MM * KDIM * 2;
    unsigned short* Wb = (unsigned short*)ws;                 // [COUT][2C] bf16
    ws += (size_t)COUT * KDIM * 2;
    unsigned short* h = (unsigned short*)ws;                  // [M][COUT] bf16
    ws += (size_t)MM * COUT * 2;
    float* sums = (float*)ws;                                 // [2*COUT]
    ws += 2 * COUT * sizeof(float);
    float* sc_sh = (float*)ws;                                // [2*COUT]

    k_zero<<<1, 2 * COUT, 0, stream>>>(sums, 2 * COUT);

    dim3 tgrid(NN / 32, CC / 32, BB);
    k_transpose_x<<<tgrid, dim3(32, 8), 0, stream>>>(x, xt);

    k_gather<<<MM / 2, 192, 0, stream>>>((const unsigned int*)xt, edge, (uint2*)xcat);

    k_wcast<<<(COUT * KDIM + 255) / 256, 256, 0, stream>>>(W, Wb);

    k_gemm<<<MM / BMT, 512, 0, stream>>>(xcat, Wb, h);

    k_stats<<<128, 192, 0, stream>>>(h, sums);

    k_bn_finalize<<<1, COUT, 0, stream>>>(sums, gamma, beta, sc_sh);

    dim3 ogrid(NN / 32, COUT / 32, BB);
    k_out<<<ogrid, dim3(32, 8), 0, stream>>>(h, sc_sh, out);
}